// Round 5
// baseline (708.158 us; speedup 1.0000x reference)
//
#include <hip/hip_runtime.h>
#include <math.h>

static constexpr int NN = 50000;   // nodes
static constexpr int EE = 800000;  // edges (< 2^20, fits eid pack)

typedef unsigned long long ull;

// ---------------- threefry2x32 (exact JAX semantics) ----------------
struct TF2 { unsigned a, b; };

__host__ __device__ __forceinline__ TF2 tf2x32(unsigned k0, unsigned k1,
                                               unsigned x0, unsigned x1) {
  unsigned k2 = k0 ^ k1 ^ 0x1BD11BDAu;
  x0 += k0; x1 += k1;
#define TFR(r) { x0 += x1; x1 = (x1 << (r)) | (x1 >> (32 - (r))); x1 ^= x0; }
  TFR(13) TFR(15) TFR(26) TFR(6)
  x0 += k1; x1 += k2 + 1u;
  TFR(17) TFR(29) TFR(16) TFR(24)
  x0 += k2; x1 += k0 + 2u;
  TFR(13) TFR(15) TFR(26) TFR(6)
  x0 += k0; x1 += k1 + 3u;
  TFR(17) TFR(29) TFR(16) TFR(24)
  x0 += k1; x1 += k2 + 4u;
  TFR(13) TFR(15) TFR(26) TFR(6)
  x0 += k2; x1 += k0 + 5u;
#undef TFR
  TF2 r; r.a = x0; r.b = x1; return r;
}

__device__ __forceinline__ float u01_bits(unsigned w) {
  float fl = __uint_as_float((w >> 9) | 0x3f800000u) - 1.0f;
  return fmaxf(1e-20f, fl + 1e-20f);
}

// bits[f] = TF(key,(0,f)).a ^ .b   (jax threefry_partitionable)
__device__ __forceinline__ float keep01(float l0, float l1, unsigned k0, unsigned k1, int node) {
  unsigned f0 = 2u * (unsigned)node, f1 = f0 + 1u;
  TF2 t0 = tf2x32(k0, k1, 0u, f0);
  TF2 t1 = tf2x32(k0, k1, 0u, f1);
  float g0 = -logf(-logf(u01_bits(t0.a ^ t0.b)));
  float g1 = -logf(-logf(u01_bits(t1.a ^ t1.b)));
  float z0 = l0 + g0, z1 = l1 + g1;   // tau == 1
  float m  = fmaxf(z0, z1);
  float e0 = expf(z0 - m), e1 = expf(z1 - m);
  float s  = e0 + e1;
  float y0 = e0 / s, y1 = e1 / s;
  return (y1 > y0) ? 0.0f : 1.0f;     // ties -> class 0, like jnp.argmax
}

// ---------------- CSR build (dst-indexed; bucket order arbitrary) ----------------
__global__ void k_count(const int* __restrict__ dst, int* __restrict__ deg, int e) {
  int i = blockIdx.x * blockDim.x + threadIdx.x;
  if (i < e) atomicAdd(&deg[dst[i]], 1);
}

__global__ void k_bsum(const int* __restrict__ deg, int* __restrict__ bsum, int n) {
  int i = blockIdx.x * 256 + threadIdx.x;
  int v = (i < n) ? deg[i] : 0;
  #pragma unroll
  for (int off = 32; off; off >>= 1) v += __shfl_xor(v, off, 64);
  __shared__ int ws[4];
  if ((threadIdx.x & 63) == 0) ws[threadIdx.x >> 6] = v;
  __syncthreads();
  if (threadIdx.x == 0) bsum[blockIdx.x] = ws[0] + ws[1] + ws[2] + ws[3];
}

__global__ void k_bscan(const int* __restrict__ bsum, int* __restrict__ bpref,
                        int nb, int* __restrict__ row_ptr, int n) {
  __shared__ int s[256];
  int t = threadIdx.x;
  int v = (t < nb) ? bsum[t] : 0;
  s[t] = v; __syncthreads();
  for (int off = 1; off < 256; off <<= 1) {
    int u = (t >= off) ? s[t - off] : 0;
    __syncthreads();
    s[t] += u;
    __syncthreads();
  }
  bpref[t] = s[t] - v;                 // exclusive
  if (t == 0) row_ptr[n] = s[255];     // total = E
}

__global__ void k_prefix(const int* __restrict__ deg, const int* __restrict__ bpref,
                         int* __restrict__ row_ptr, int* __restrict__ cursor, int n) {
  __shared__ int s[256];
  int t = threadIdx.x;
  int i = blockIdx.x * 256 + t;
  int v = (i < n) ? deg[i] : 0;
  s[t] = v; __syncthreads();
  for (int off = 1; off < 256; off <<= 1) {
    int u = (t >= off) ? s[t - off] : 0;
    __syncthreads();
    s[t] += u;
    __syncthreads();
  }
  if (i < n) {
    int ex = s[t] - v + bpref[blockIdx.x];
    row_ptr[i] = ex; cursor[i] = ex;
  }
}

// pack (src, edge_id): key = src<<20 | eid
__global__ void k_fill(const int* __restrict__ src, const int* __restrict__ dst,
                       int* __restrict__ cursor, ull* __restrict__ ce, int e) {
  int i = blockIdx.x * blockDim.x + threadIdx.x;
  if (i < e) {
    int pos = atomicAdd(&cursor[dst[i]], 1);
    ce[pos] = ((ull)(unsigned)src[i] << 20) | (unsigned)i;
  }
}

// ---------------- dense / fused kernels ----------------
// encoder + fused LayerNorm
__global__ void k_enc_ln(const float* __restrict__ x, const float* __restrict__ W,
                         const float* __restrict__ bias, const float* __restrict__ g,
                         const float* __restrict__ bb, float* __restrict__ hln) {
  __shared__ float Ws[64 * 64];
  for (int i = threadIdx.x; i < 64 * 64; i += 256) Ws[i] = W[i];
  __syncthreads();
  int node = blockIdx.x * 4 + (threadIdx.x >> 6);
  int j = threadIdx.x & 63;
  const float* xr = x + (size_t)node * 64;
  float s = bias[j];
  #pragma unroll
  for (int i = 0; i < 64; i++) s = fmaf(xr[i], Ws[i * 64 + j], s);
  float t = s;
  #pragma unroll
  for (int off = 32; off; off >>= 1) t += __shfl_xor(t, off, 64);
  float mu = t * (1.0f / 64.0f);
  float d = s - mu;
  float q = d * d;
  #pragma unroll
  for (int off = 32; off; off >>= 1) q += __shfl_xor(q, off, 64);
  float rs = 1.0f / sqrtf(q * (1.0f / 64.0f) + 1e-5f);
  hln[(size_t)node * 64 + j] = d * rs * g[j] + bb[j];
}

// proj: P1 = hln @ W1[64:128] (agg side), S1 = hln @ W1[0:64] (self side), both nets
// lane: h=lane>>5 (0=self,1=agg), jo=lane&31 (col; <16 in-net, >=16 out-net)
__global__ void k_proj(const float* __restrict__ hln,
                       const float* __restrict__ W1i, const float* __restrict__ W1o,
                       float* __restrict__ P1, float* __restrict__ S1, int nchunk) {
  int t = threadIdx.x, w = t >> 6, lane = t & 63;
  int h = lane >> 5, jo = lane & 31;
  const float* Wg = (jo < 16) ? W1i : W1o;
  int col = jo & 15;
  float wr[64];
  #pragma unroll
  for (int i = 0; i < 64; i++) wr[i] = Wg[(h * 64 + i) * 16 + col];
  __shared__ float st[256];
  for (int blk = blockIdx.x; blk < nchunk; blk += gridDim.x) {
    __syncthreads();                    // protect st reuse across iterations
    st[t] = hln[(size_t)blk * 256 + t]; // 4 nodes, coalesced
    __syncthreads();
    const float* sv = &st[w * 64];
    float a = 0.f;
    #pragma unroll
    for (int i = 0; i < 64; i++) a = fmaf(sv[i], wr[i], a);
    size_t node = (size_t)blk * 4 + w;
    if (h == 0) S1[node * 32 + jo] = a;
    else        P1[node * 32 + jo] = a;
  }
}

// gatherA: agg32 of P1 + S1 -> r (regs only) -> project to P2S2 [N,8]
// P2S2 row: [p2i0,p2i1,p2o0,p2o1, s2i0,s2i1,s2o0,s2o1]
__global__ void k_gatherA(const float* __restrict__ P1, const float* __restrict__ S1,
                          const int* __restrict__ row_ptr, const ull* __restrict__ ce,
                          const float* __restrict__ inb1, const float* __restrict__ outb1,
                          const float* __restrict__ inW2, const float* __restrict__ outW2,
                          float* __restrict__ P2S2) {
  int t = threadIdx.x;
  int w = t >> 6, lane = t & 63;
  int sub = lane >> 5, j = lane & 31;
  int node = blockIdx.x * 8 + w * 2 + sub;
  int b = row_ptr[node], e = row_ptr[node + 1];
  float s0 = 0.f, s1 = 0.f;
  for (int base = b; base < e; base += 32) {
    int idx = base + j;
    int u_l = (idx < e) ? (int)(ce[idx] >> 20) : 0;
    int cnt = min(32, e - base);
    int k = 0;
    for (; k + 2 <= cnt; k += 2) {
      int u0 = __shfl(u_l, k, 32), u1 = __shfl(u_l, k + 1, 32);
      s0 += P1[(size_t)u0 * 32 + j];
      s1 += P1[(size_t)u1 * 32 + j];
    }
    if (k < cnt) s0 += P1[(size_t)__shfl(u_l, k, 32) * 32 + j];
  }
  float agg = s0 + s1;
  float b1j = (j < 16) ? inb1[j] : outb1[j - 16];
  float rj = fmaxf(S1[(size_t)node * 32 + j] + agg + b1j, 0.f);
  // conv2 projections: self-side rows [0:16], agg-side rows [16:32]
  float wa0, wa1, wb0, wb1;
  if (j < 16) {
    wa0 = inW2[j * 2 + 0];  wa1 = inW2[j * 2 + 1];
    wb0 = inW2[(16 + j) * 2 + 0];  wb1 = inW2[(16 + j) * 2 + 1];
  } else {
    int j2 = j - 16;
    wa0 = outW2[j2 * 2 + 0];  wa1 = outW2[j2 * 2 + 1];
    wb0 = outW2[(16 + j2) * 2 + 0];  wb1 = outW2[(16 + j2) * 2 + 1];
  }
  float v0 = rj * wa0, v1 = rj * wa1, v2 = rj * wb0, v3 = rj * wb1;
  #pragma unroll
  for (int off = 8; off; off >>= 1) {   // reduce within 16-lane group
    v0 += __shfl_xor(v0, off, 64);
    v1 += __shfl_xor(v1, off, 64);
    v2 += __shfl_xor(v2, off, 64);
    v3 += __shfl_xor(v3, off, 64);
  }
  float* row = P2S2 + (size_t)node * 8;
  if (j == 0)  { row[0] = v2; row[1] = v3; row[4] = v0; row[5] = v1; }  // in-net
  if (j == 16) { row[2] = v2; row[3] = v3; row[6] = v0; row[7] = v1; }  // out-net
}

// gatherB: 16B/edge gather of P2 + self S2 -> logits -> gumbel decisions
__global__ void k_gatherB(const float* __restrict__ P2S2, const int* __restrict__ row_ptr,
                          const ull* __restrict__ ce,
                          const float* __restrict__ inb2, const float* __restrict__ outb2,
                          float* __restrict__ keep_in, float* __restrict__ keep_out,
                          unsigned ki0, unsigned ki1, unsigned ko0, unsigned ko1) {
  int t = threadIdx.x;
  int w = t >> 6, lane = t & 63;
  int g = lane >> 4, el = lane & 15;
  int node = blockIdx.x * 16 + w * 4 + g;
  int b = row_ptr[node], e = row_ptr[node + 1];
  float a0 = 0.f, a1 = 0.f, a2 = 0.f, a3 = 0.f;
  for (int base = b; base < e; base += 16) {
    int idx = base + el;
    if (idx < e) {
      int u = (int)(ce[idx] >> 20);
      float4 p = *(const float4*)(P2S2 + (size_t)u * 8);
      a0 += p.x; a1 += p.y; a2 += p.z; a3 += p.w;
    }
  }
  #pragma unroll
  for (int off = 8; off; off >>= 1) {   // reduce within 16-lane group
    a0 += __shfl_xor(a0, off, 64);
    a1 += __shfl_xor(a1, off, 64);
    a2 += __shfl_xor(a2, off, 64);
    a3 += __shfl_xor(a3, off, 64);
  }
  float4 sf = *(const float4*)(P2S2 + (size_t)node * 8 + 4);
  if (el == 0)
    keep_in[node]  = keep01(sf.x + a0 + inb2[0],  sf.y + a1 + inb2[1],  ki0, ki1, node);
  else if (el == 1)
    keep_out[node] = keep01(sf.z + a2 + outb2[0], sf.w + a3 + outb2[1], ko0, ko1, node);
}

// C: weighted agg64 (+ew write) + env conv (W in LDS) + optional LN
template <bool LN>
__global__ void k_aggC(const float* __restrict__ hln, const int* __restrict__ row_ptr,
                       const ull* __restrict__ ce, const float* __restrict__ keep_in,
                       const float* __restrict__ keep_out, float* __restrict__ ew,
                       const float* __restrict__ W, const float* __restrict__ bias,
                       const float* __restrict__ g, const float* __restrict__ bb,
                       float* __restrict__ hout) {
  __shared__ float Ws[128 * 64];                 // 32 KiB, reused by 4 waves
  __shared__ __align__(16) float st[4][128];
  int t = threadIdx.x;
  for (int i = t; i < 128 * 64; i += 256) Ws[i] = W[i];
  __syncthreads();
  int w = t >> 6, lane = t & 63;
  int node = blockIdx.x * 4 + w;
  float ki = keep_in[node];
  float hv = hln[(size_t)node * 64 + lane];
  int b = row_ptr[node], e = row_ptr[node + 1];
  float s0 = 0.f, s1 = 0.f, s2 = 0.f, s3 = 0.f;
  for (int base = b; base < e; base += 64) {
    int idx = base + lane;
    int u_l = 0; float ko_l = 0.f;
    if (idx < e) {
      ull c = ce[idx];
      u_l = (int)(c >> 20);
      ko_l = keep_out[u_l];
      ew[(unsigned)(c & 0xFFFFFu)] = ki * ko_l;   // exact {0,1} product
    }
    if (ki != 0.f) {                              // wave-uniform skip
      int cnt = min(64, e - base);
      int k = 0;
      for (; k + 4 <= cnt; k += 4) {
        int u0 = __shfl(u_l, k, 64),     u1 = __shfl(u_l, k + 1, 64),
            u2 = __shfl(u_l, k + 2, 64), u3 = __shfl(u_l, k + 3, 64);
        float w0 = __shfl(ko_l, k, 64),     w1 = __shfl(ko_l, k + 1, 64),
              w2 = __shfl(ko_l, k + 2, 64), w3 = __shfl(ko_l, k + 3, 64);
        if (w0 != 0.f) s0 += hln[(size_t)u0 * 64 + lane];  // uniform branches
        if (w1 != 0.f) s1 += hln[(size_t)u1 * 64 + lane];
        if (w2 != 0.f) s2 += hln[(size_t)u2 * 64 + lane];
        if (w3 != 0.f) s3 += hln[(size_t)u3 * 64 + lane];
      }
      for (; k < cnt; k++) {
        int u0 = __shfl(u_l, k, 64);
        float w0 = __shfl(ko_l, k, 64);
        if (w0 != 0.f) s0 += hln[(size_t)u0 * 64 + lane];
      }
    }
  }
  float s = ((s0 + s1) + (s2 + s3)) * ki;
  st[w][lane]      = hv;
  st[w][64 + lane] = s;
  // no __syncthreads needed: st[w] is wave-private (same-wave RAW via lgkmcnt)
  float a0 = bias[lane], a1 = 0.f, a2 = 0.f, a3 = 0.f;
  #pragma unroll 4
  for (int i = 0; i < 128; i += 4) {
    float4 c4 = *(const float4*)(&st[w][i]);
    a0 = fmaf(c4.x, Ws[(i    ) * 64 + lane], a0);
    a1 = fmaf(c4.y, Ws[(i + 1) * 64 + lane], a1);
    a2 = fmaf(c4.z, Ws[(i + 2) * 64 + lane], a2);
    a3 = fmaf(c4.w, Ws[(i + 3) * 64 + lane], a3);
  }
  float acc = (a0 + a1) + (a2 + a3);
  if (LN) {
    float tt = acc;
    #pragma unroll
    for (int off = 32; off; off >>= 1) tt += __shfl_xor(tt, off, 64);
    float mu = tt * (1.0f / 64.0f);
    float d = acc - mu;
    float q = d * d;
    #pragma unroll
    for (int off = 32; off; off >>= 1) q += __shfl_xor(q, off, 64);
    float rs = 1.0f / sqrtf(q * (1.0f / 64.0f) + 1e-5f);
    hout[(size_t)node * 64 + lane] = d * rs * g[lane] + bb[lane];
  } else {
    hout[(size_t)node * 64 + lane] = acc;
  }
}

__global__ void k_dec(const float* __restrict__ h, const float* __restrict__ W,
                      const float* __restrict__ bias, float* __restrict__ out) {
  __shared__ float Ws[64 * 32];
  int t = threadIdx.x;
  for (int i = t; i < 64 * 32; i += 256) Ws[i] = W[i];
  __syncthreads();
  int node = blockIdx.x * 8 + (t >> 5);
  int j = t & 31;
  const float* hr = h + (size_t)node * 64;
  float s = bias[j];
  #pragma unroll
  for (int i = 0; i < 64; i++) s = fmaf(hr[i], Ws[i * 32 + j], s);
  out[(size_t)node * 32 + j] = s;
}

// ---------------- launcher ----------------
extern "C" void kernel_launch(void* const* d_in, const int* in_sizes, int n_in,
                              void* d_out, int out_size, void* d_ws, size_t ws_size,
                              hipStream_t stream) {
  const float* x      = (const float*)d_in[0];
  const int*   ei     = (const int*)  d_in[1];
  const float* W_enc  = (const float*)d_in[2];
  const float* b_enc  = (const float*)d_in[3];
  const float* env_W  = (const float*)d_in[4];  // [3,128,64]
  const float* env_b  = (const float*)d_in[5];  // [3,64]
  const float* W_dec  = (const float*)d_in[6];
  const float* b_dec  = (const float*)d_in[7];
  const float* ln_g   = (const float*)d_in[8];
  const float* ln_b   = (const float*)d_in[9];
  const float* in_W1  = (const float*)d_in[10];
  const float* in_b1  = (const float*)d_in[11];
  const float* in_W2  = (const float*)d_in[12];
  const float* in_b2  = (const float*)d_in[13];
  const float* out_W1 = (const float*)d_in[14];
  const float* out_b1 = (const float*)d_in[15];
  const float* out_W2 = (const float*)d_in[16];
  const float* out_b2 = (const float*)d_in[17];

  const int n = NN, e = EE;
  const int* src = ei;
  const int* dst = ei + e;

  float* out_h  = (float*)d_out;            // [N,32]
  float* out_ew = out_h + (size_t)n * 32;   // [3,E]

  size_t off = 0;
  auto alloc = [&](size_t bytes) -> void* {
    void* p = (char*)d_ws + off;
    off += (bytes + 255) & ~(size_t)255;
    return p;
  };
  float* hlnA    = (float*)alloc((size_t)n * 64 * 4);
  float* hlnB    = (float*)alloc((size_t)n * 64 * 4);
  float* P1      = (float*)alloc((size_t)n * 32 * 4);
  float* S1      = (float*)alloc((size_t)n * 32 * 4);
  float* P2S2    = (float*)alloc((size_t)n * 8 * 4);
  float* keep_i  = (float*)alloc((size_t)n * 4);
  float* keep_o  = (float*)alloc((size_t)n * 4);
  int*   deg     = (int*)alloc((size_t)n * 4);
  int*   row_ptr = (int*)alloc((size_t)(n + 1) * 4);
  int*   cursor  = (int*)alloc((size_t)n * 4);
  int*   bsum    = (int*)alloc(256 * 4);
  int*   bpref   = (int*)alloc(256 * 4);
  ull*   ce      = (ull*)alloc((size_t)e * 8);
  if (off > ws_size) return;  // ws too small: bail loudly

  const int nb = (n + 255) / 256;  // 196

  hipMemsetAsync(deg, 0, (size_t)n * 4, stream);
  k_count<<<(e + 255) / 256, 256, 0, stream>>>(dst, deg, e);
  k_bsum<<<nb, 256, 0, stream>>>(deg, bsum, n);
  k_bscan<<<1, 256, 0, stream>>>(bsum, bpref, nb, row_ptr, n);
  k_prefix<<<nb, 256, 0, stream>>>(deg, bpref, row_ptr, cursor, n);
  k_fill<<<(e + 255) / 256, 256, 0, stream>>>(src, dst, cursor, ce, e);

  const int g4  = n / 4;    // 12500 (N%4==0)
  const int g8  = n / 8;    // 6250
  const int g16 = n / 16;   // 3125

  k_enc_ln<<<g4, 256, 0, stream>>>(x, W_enc, b_enc, ln_g, ln_b, hlnA);

  float* hln = hlnA;
  float* hln_next = hlnB;
  for (int l = 0; l < 3; l++) {
    TF2 kin  = tf2x32(0u, 1234u, 0u, (unsigned)(2 * l));      // fold_in(key(1234), 2l)
    TF2 kout = tf2x32(0u, 1234u, 0u, (unsigned)(2 * l + 1));  // fold_in(key(1234), 2l+1)

    k_proj<<<1250, 256, 0, stream>>>(hln, in_W1, out_W1, P1, S1, g4);
    k_gatherA<<<g8, 256, 0, stream>>>(P1, S1, row_ptr, ce, in_b1, out_b1,
                                      in_W2, out_W2, P2S2);
    k_gatherB<<<g16, 256, 0, stream>>>(P2S2, row_ptr, ce, in_b2, out_b2,
                                       keep_i, keep_o, kin.a, kin.b, kout.a, kout.b);
    if (l < 2) {
      k_aggC<true><<<g4, 256, 0, stream>>>(hln, row_ptr, ce, keep_i, keep_o,
                                           out_ew + (size_t)l * e,
                                           env_W + (size_t)l * 128 * 64,
                                           env_b + (size_t)l * 64, ln_g, ln_b, hln_next);
    } else {
      k_aggC<false><<<g4, 256, 0, stream>>>(hln, row_ptr, ce, keep_i, keep_o,
                                            out_ew + (size_t)l * e,
                                            env_W + (size_t)l * 128 * 64,
                                            env_b + (size_t)l * 64, ln_g, ln_b, hln_next);
    }
    float* tmp = hln; hln = hln_next; hln_next = tmp;
  }

  k_dec<<<g8, 256, 0, stream>>>(hln, W_dec, b_dec, out_h);
}

// Round 6
// 642.972 us; speedup vs baseline: 1.1014x; 1.1014x over previous
//
#include <hip/hip_runtime.h>
#include <math.h>

static constexpr int NN = 50000;   // nodes
static constexpr int EE = 800000;  // edges (< 2^20, fits eid pack)

typedef unsigned long long ull;

// ---------------- threefry2x32 (exact JAX semantics) ----------------
struct TF2 { unsigned a, b; };

__host__ __device__ __forceinline__ TF2 tf2x32(unsigned k0, unsigned k1,
                                               unsigned x0, unsigned x1) {
  unsigned k2 = k0 ^ k1 ^ 0x1BD11BDAu;
  x0 += k0; x1 += k1;
#define TFR(r) { x0 += x1; x1 = (x1 << (r)) | (x1 >> (32 - (r))); x1 ^= x0; }
  TFR(13) TFR(15) TFR(26) TFR(6)
  x0 += k1; x1 += k2 + 1u;
  TFR(17) TFR(29) TFR(16) TFR(24)
  x0 += k2; x1 += k0 + 2u;
  TFR(13) TFR(15) TFR(26) TFR(6)
  x0 += k0; x1 += k1 + 3u;
  TFR(17) TFR(29) TFR(16) TFR(24)
  x0 += k1; x1 += k2 + 4u;
  TFR(13) TFR(15) TFR(26) TFR(6)
  x0 += k2; x1 += k0 + 5u;
#undef TFR
  TF2 r; r.a = x0; r.b = x1; return r;
}

__device__ __forceinline__ float u01_bits(unsigned w) {
  float fl = __uint_as_float((w >> 9) | 0x3f800000u) - 1.0f;
  return fmaxf(1e-20f, fl + 1e-20f);
}

// bits[f] = TF(key,(0,f)).a ^ .b   (jax threefry_partitionable)
__device__ __forceinline__ float keep01(float l0, float l1, unsigned k0, unsigned k1, int node) {
  unsigned f0 = 2u * (unsigned)node, f1 = f0 + 1u;
  TF2 t0 = tf2x32(k0, k1, 0u, f0);
  TF2 t1 = tf2x32(k0, k1, 0u, f1);
  float g0 = -logf(-logf(u01_bits(t0.a ^ t0.b)));
  float g1 = -logf(-logf(u01_bits(t1.a ^ t1.b)));
  float z0 = l0 + g0, z1 = l1 + g1;   // tau == 1
  float m  = fmaxf(z0, z1);
  float e0 = expf(z0 - m), e1 = expf(z1 - m);
  float s  = e0 + e1;
  float y0 = e0 / s, y1 = e1 / s;
  return (y1 > y0) ? 0.0f : 1.0f;     // ties -> class 0, like jnp.argmax
}

// ---------------- CSR build (dst-indexed; bucket order arbitrary) ----------------
__global__ void k_count(const int* __restrict__ dst, int* __restrict__ deg, int e) {
  int i = blockIdx.x * blockDim.x + threadIdx.x;
  if (i < e) atomicAdd(&deg[dst[i]], 1);
}

__global__ void k_bsum(const int* __restrict__ deg, int* __restrict__ bsum, int n) {
  int i = blockIdx.x * 256 + threadIdx.x;
  int v = (i < n) ? deg[i] : 0;
  #pragma unroll
  for (int off = 32; off; off >>= 1) v += __shfl_xor(v, off, 64);
  __shared__ int ws[4];
  if ((threadIdx.x & 63) == 0) ws[threadIdx.x >> 6] = v;
  __syncthreads();
  if (threadIdx.x == 0) bsum[blockIdx.x] = ws[0] + ws[1] + ws[2] + ws[3];
}

__global__ void k_bscan(const int* __restrict__ bsum, int* __restrict__ bpref,
                        int nb, int* __restrict__ row_ptr, int n) {
  __shared__ int s[256];
  int t = threadIdx.x;
  int v = (t < nb) ? bsum[t] : 0;
  s[t] = v; __syncthreads();
  for (int off = 1; off < 256; off <<= 1) {
    int u = (t >= off) ? s[t - off] : 0;
    __syncthreads();
    s[t] += u;
    __syncthreads();
  }
  bpref[t] = s[t] - v;                 // exclusive
  if (t == 0) row_ptr[n] = s[255];     // total = E
}

__global__ void k_prefix(const int* __restrict__ deg, const int* __restrict__ bpref,
                         int* __restrict__ row_ptr, int* __restrict__ cursor, int n) {
  __shared__ int s[256];
  int t = threadIdx.x;
  int i = blockIdx.x * 256 + t;
  int v = (i < n) ? deg[i] : 0;
  s[t] = v; __syncthreads();
  for (int off = 1; off < 256; off <<= 1) {
    int u = (t >= off) ? s[t - off] : 0;
    __syncthreads();
    s[t] += u;
    __syncthreads();
  }
  if (i < n) {
    int ex = s[t] - v + bpref[blockIdx.x];
    row_ptr[i] = ex; cursor[i] = ex;
  }
}

// pack (src, edge_id): key = src<<20 | eid
__global__ void k_fill(const int* __restrict__ src, const int* __restrict__ dst,
                       int* __restrict__ cursor, ull* __restrict__ ce, int e) {
  int i = blockIdx.x * blockDim.x + threadIdx.x;
  if (i < e) {
    int pos = atomicAdd(&cursor[dst[i]], 1);
    ce[pos] = ((ull)(unsigned)src[i] << 20) | (unsigned)i;
  }
}

// ---------------- dense / fused kernels ----------------
// encoder + fused LayerNorm
__global__ void k_enc_ln(const float* __restrict__ x, const float* __restrict__ W,
                         const float* __restrict__ bias, const float* __restrict__ g,
                         const float* __restrict__ bb, float* __restrict__ hln) {
  __shared__ float Ws[64 * 64];
  for (int i = threadIdx.x; i < 64 * 64; i += 256) Ws[i] = W[i];
  __syncthreads();
  int node = blockIdx.x * 4 + (threadIdx.x >> 6);
  int j = threadIdx.x & 63;
  const float* xr = x + (size_t)node * 64;
  float s = bias[j];
  #pragma unroll
  for (int i = 0; i < 64; i++) s = fmaf(xr[i], Ws[i * 64 + j], s);
  float t = s;
  #pragma unroll
  for (int off = 32; off; off >>= 1) t += __shfl_xor(t, off, 64);
  float mu = t * (1.0f / 64.0f);
  float d = s - mu;
  float q = d * d;
  #pragma unroll
  for (int off = 32; off; off >>= 1) q += __shfl_xor(q, off, 64);
  float rs = 1.0f / sqrtf(q * (1.0f / 64.0f) + 1e-5f);
  hln[(size_t)node * 64 + j] = d * rs * g[j] + bb[j];
}

// proj: P1 = hln @ W1[64:128] (agg side), S1 = hln @ W1[0:64] (self side), both nets
__global__ void k_proj(const float* __restrict__ hln,
                       const float* __restrict__ W1i, const float* __restrict__ W1o,
                       float* __restrict__ P1, float* __restrict__ S1, int nchunk) {
  int t = threadIdx.x, w = t >> 6, lane = t & 63;
  int h = lane >> 5, jo = lane & 31;
  const float* Wg = (jo < 16) ? W1i : W1o;
  int col = jo & 15;
  float wr[64];
  #pragma unroll
  for (int i = 0; i < 64; i++) wr[i] = Wg[(h * 64 + i) * 16 + col];
  __shared__ float st[256];
  for (int blk = blockIdx.x; blk < nchunk; blk += gridDim.x) {
    __syncthreads();                    // protect st reuse across iterations
    st[t] = hln[(size_t)blk * 256 + t]; // 4 nodes, coalesced
    __syncthreads();
    const float* sv = &st[w * 64];
    float a = 0.f;
    #pragma unroll
    for (int i = 0; i < 64; i++) a = fmaf(sv[i], wr[i], a);
    size_t node = (size_t)blk * 4 + w;
    if (h == 0) S1[node * 32 + jo] = a;
    else        P1[node * 32 + jo] = a;
  }
}

// projE: Htop = hln @ W[0:64] + env_b ; Pbot = hln @ W[64:128]   (env conv split)
__global__ void k_projE(const float* __restrict__ hln, const float* __restrict__ W,
                        const float* __restrict__ bias,
                        float* __restrict__ Htop, float* __restrict__ Pbot, int nchunk) {
  __shared__ float Ws[128 * 64];   // 32 KiB, loaded once per block lifetime
  __shared__ float st[256];
  int t = threadIdx.x;
  for (int i = t; i < 128 * 64; i += 256) Ws[i] = W[i];
  int w = t >> 6, lane = t & 63;
  float bj = bias[lane];
  for (int blk = blockIdx.x; blk < nchunk; blk += gridDim.x) {
    __syncthreads();                    // Ws ready / st reuse safe
    st[t] = hln[(size_t)blk * 256 + t];
    __syncthreads();
    const float* sv = &st[w * 64];
    float a = bj, b = 0.f;
    #pragma unroll
    for (int i = 0; i < 64; i++) {
      float hv = sv[i];
      a = fmaf(hv, Ws[i * 64 + lane], a);          // top half (self)
      b = fmaf(hv, Ws[(64 + i) * 64 + lane], b);   // bottom half (agg side)
    }
    size_t node = (size_t)blk * 4 + w;
    Htop[node * 64 + lane] = a;
    Pbot[node * 64 + lane] = b;
  }
}

// gatherA: agg32 of P1 + S1 -> r (regs only) -> project to P2S2 [N,8]
// P2S2 row: [p2i0,p2i1,p2o0,p2o1, s2i0,s2i1,s2o0,s2o1]
__global__ void k_gatherA(const float* __restrict__ P1, const float* __restrict__ S1,
                          const int* __restrict__ row_ptr, const ull* __restrict__ ce,
                          const float* __restrict__ inb1, const float* __restrict__ outb1,
                          const float* __restrict__ inW2, const float* __restrict__ outW2,
                          float* __restrict__ P2S2) {
  int t = threadIdx.x;
  int w = t >> 6, lane = t & 63;
  int sub = lane >> 5, j = lane & 31;
  int node = blockIdx.x * 8 + w * 2 + sub;
  int b = row_ptr[node], e = row_ptr[node + 1];
  float s0 = 0.f, s1 = 0.f;
  for (int base = b; base < e; base += 32) {
    int idx = base + j;
    int u_l = (idx < e) ? (int)(ce[idx] >> 20) : 0;
    int cnt = min(32, e - base);
    int k = 0;
    for (; k + 2 <= cnt; k += 2) {
      int u0 = __shfl(u_l, k, 32), u1 = __shfl(u_l, k + 1, 32);
      s0 += P1[(size_t)u0 * 32 + j];
      s1 += P1[(size_t)u1 * 32 + j];
    }
    if (k < cnt) s0 += P1[(size_t)__shfl(u_l, k, 32) * 32 + j];
  }
  float agg = s0 + s1;
  float b1j = (j < 16) ? inb1[j] : outb1[j - 16];
  float rj = fmaxf(S1[(size_t)node * 32 + j] + agg + b1j, 0.f);
  float wa0, wa1, wb0, wb1;
  if (j < 16) {
    wa0 = inW2[j * 2 + 0];  wa1 = inW2[j * 2 + 1];
    wb0 = inW2[(16 + j) * 2 + 0];  wb1 = inW2[(16 + j) * 2 + 1];
  } else {
    int j2 = j - 16;
    wa0 = outW2[j2 * 2 + 0];  wa1 = outW2[j2 * 2 + 1];
    wb0 = outW2[(16 + j2) * 2 + 0];  wb1 = outW2[(16 + j2) * 2 + 1];
  }
  float v0 = rj * wa0, v1 = rj * wa1, v2 = rj * wb0, v3 = rj * wb1;
  #pragma unroll
  for (int off = 8; off; off >>= 1) {   // reduce within 16-lane group
    v0 += __shfl_xor(v0, off, 64);
    v1 += __shfl_xor(v1, off, 64);
    v2 += __shfl_xor(v2, off, 64);
    v3 += __shfl_xor(v3, off, 64);
  }
  float* row = P2S2 + (size_t)node * 8;
  if (j == 0)  { row[0] = v2; row[1] = v3; row[4] = v0; row[5] = v1; }  // in-net
  if (j == 16) { row[2] = v2; row[3] = v3; row[6] = v0; row[7] = v1; }  // out-net
}

// gatherB: 16B/edge gather of P2 + self S2 -> logits -> gumbel decisions
__global__ void k_gatherB(const float* __restrict__ P2S2, const int* __restrict__ row_ptr,
                          const ull* __restrict__ ce,
                          const float* __restrict__ inb2, const float* __restrict__ outb2,
                          float* __restrict__ keep_in, float* __restrict__ keep_out,
                          unsigned ki0, unsigned ki1, unsigned ko0, unsigned ko1) {
  int t = threadIdx.x;
  int w = t >> 6, lane = t & 63;
  int g = lane >> 4, el = lane & 15;
  int node = blockIdx.x * 16 + w * 4 + g;
  int b = row_ptr[node], e = row_ptr[node + 1];
  float a0 = 0.f, a1 = 0.f, a2 = 0.f, a3 = 0.f;
  for (int base = b; base < e; base += 16) {
    int idx = base + el;
    if (idx < e) {
      int u = (int)(ce[idx] >> 20);
      float4 p = *(const float4*)(P2S2 + (size_t)u * 8);
      a0 += p.x; a1 += p.y; a2 += p.z; a3 += p.w;
    }
  }
  #pragma unroll
  for (int off = 8; off; off >>= 1) {   // reduce within 16-lane group
    a0 += __shfl_xor(a0, off, 64);
    a1 += __shfl_xor(a1, off, 64);
    a2 += __shfl_xor(a2, off, 64);
    a3 += __shfl_xor(a3, off, 64);
  }
  float4 sf = *(const float4*)(P2S2 + (size_t)node * 8 + 4);
  if (el == 0)
    keep_in[node]  = keep01(sf.x + a0 + inb2[0],  sf.y + a1 + inb2[1],  ki0, ki1, node);
  else if (el == 1)
    keep_out[node] = keep01(sf.z + a2 + outb2[0], sf.w + a3 + outb2[1], ko0, ko1, node);
}

// D: weighted gather of Pbot (+ew write) + Htop add + optional LN.  No LDS, no W.
template <bool LN>
__global__ void k_aggD(const float* __restrict__ Htop, const float* __restrict__ Pbot,
                       const int* __restrict__ row_ptr, const ull* __restrict__ ce,
                       const float* __restrict__ keep_in, const float* __restrict__ keep_out,
                       float* __restrict__ ew, const float* __restrict__ g,
                       const float* __restrict__ bb, float* __restrict__ hout) {
  int t = threadIdx.x;
  int w = t >> 6, lane = t & 63;
  int node = blockIdx.x * 4 + w;
  float ki = keep_in[node];
  int b = row_ptr[node], e = row_ptr[node + 1];
  float s0 = 0.f, s1 = 0.f, s2 = 0.f, s3 = 0.f;
  for (int base = b; base < e; base += 64) {
    int idx = base + lane;
    int u_l = 0; float ko_l = 0.f;
    if (idx < e) {
      ull c = ce[idx];
      u_l = (int)(c >> 20);
      ko_l = keep_out[u_l];
      ew[(unsigned)(c & 0xFFFFFu)] = ki * ko_l;   // exact {0,1} product
    }
    if (ki != 0.f) {                              // wave-uniform skip
      int cnt = min(64, e - base);
      int k = 0;
      for (; k + 4 <= cnt; k += 4) {
        int u0 = __shfl(u_l, k, 64),     u1 = __shfl(u_l, k + 1, 64),
            u2 = __shfl(u_l, k + 2, 64), u3 = __shfl(u_l, k + 3, 64);
        float w0 = __shfl(ko_l, k, 64),     w1 = __shfl(ko_l, k + 1, 64),
              w2 = __shfl(ko_l, k + 2, 64), w3 = __shfl(ko_l, k + 3, 64);
        if (w0 != 0.f) s0 += Pbot[(size_t)u0 * 64 + lane];  // uniform branches
        if (w1 != 0.f) s1 += Pbot[(size_t)u1 * 64 + lane];
        if (w2 != 0.f) s2 += Pbot[(size_t)u2 * 64 + lane];
        if (w3 != 0.f) s3 += Pbot[(size_t)u3 * 64 + lane];
      }
      for (; k < cnt; k++) {
        int u0 = __shfl(u_l, k, 64);
        float w0 = __shfl(ko_l, k, 64);
        if (w0 != 0.f) s0 += Pbot[(size_t)u0 * 64 + lane];
      }
    }
  }
  float acc = Htop[(size_t)node * 64 + lane] + ((s0 + s1) + (s2 + s3)) * ki;
  if (LN) {
    float tt = acc;
    #pragma unroll
    for (int off = 32; off; off >>= 1) tt += __shfl_xor(tt, off, 64);
    float mu = tt * (1.0f / 64.0f);
    float d = acc - mu;
    float q = d * d;
    #pragma unroll
    for (int off = 32; off; off >>= 1) q += __shfl_xor(q, off, 64);
    float rs = 1.0f / sqrtf(q * (1.0f / 64.0f) + 1e-5f);
    hout[(size_t)node * 64 + lane] = d * rs * g[lane] + bb[lane];
  } else {
    hout[(size_t)node * 64 + lane] = acc;
  }
}

__global__ void k_dec(const float* __restrict__ h, const float* __restrict__ W,
                      const float* __restrict__ bias, float* __restrict__ out) {
  __shared__ float Ws[64 * 32];
  int t = threadIdx.x;
  for (int i = t; i < 64 * 32; i += 256) Ws[i] = W[i];
  __syncthreads();
  int node = blockIdx.x * 8 + (t >> 5);
  int j = t & 31;
  const float* hr = h + (size_t)node * 64;
  float s = bias[j];
  #pragma unroll
  for (int i = 0; i < 64; i++) s = fmaf(hr[i], Ws[i * 32 + j], s);
  out[(size_t)node * 32 + j] = s;
}

// ---------------- launcher ----------------
extern "C" void kernel_launch(void* const* d_in, const int* in_sizes, int n_in,
                              void* d_out, int out_size, void* d_ws, size_t ws_size,
                              hipStream_t stream) {
  const float* x      = (const float*)d_in[0];
  const int*   ei     = (const int*)  d_in[1];
  const float* W_enc  = (const float*)d_in[2];
  const float* b_enc  = (const float*)d_in[3];
  const float* env_W  = (const float*)d_in[4];  // [3,128,64]
  const float* env_b  = (const float*)d_in[5];  // [3,64]
  const float* W_dec  = (const float*)d_in[6];
  const float* b_dec  = (const float*)d_in[7];
  const float* ln_g   = (const float*)d_in[8];
  const float* ln_b   = (const float*)d_in[9];
  const float* in_W1  = (const float*)d_in[10];
  const float* in_b1  = (const float*)d_in[11];
  const float* in_W2  = (const float*)d_in[12];
  const float* in_b2  = (const float*)d_in[13];
  const float* out_W1 = (const float*)d_in[14];
  const float* out_b1 = (const float*)d_in[15];
  const float* out_W2 = (const float*)d_in[16];
  const float* out_b2 = (const float*)d_in[17];

  const int n = NN, e = EE;
  const int* src = ei;
  const int* dst = ei + e;

  float* out_h  = (float*)d_out;            // [N,32]
  float* out_ew = out_h + (size_t)n * 32;   // [3,E]

  size_t off = 0;
  auto alloc = [&](size_t bytes) -> void* {
    void* p = (char*)d_ws + off;
    off += (bytes + 255) & ~(size_t)255;
    return p;
  };
  float* hlnA    = (float*)alloc((size_t)n * 64 * 4);
  float* hlnB    = (float*)alloc((size_t)n * 64 * 4);
  float* Htop    = (float*)alloc((size_t)n * 64 * 4);
  float* Pbot    = (float*)alloc((size_t)n * 64 * 4);
  float* P1      = (float*)alloc((size_t)n * 32 * 4);
  float* S1      = (float*)alloc((size_t)n * 32 * 4);
  float* P2S2    = (float*)alloc((size_t)n * 8 * 4);
  float* keep_i  = (float*)alloc((size_t)n * 4);
  float* keep_o  = (float*)alloc((size_t)n * 4);
  int*   deg     = (int*)alloc((size_t)n * 4);
  int*   row_ptr = (int*)alloc((size_t)(n + 1) * 4);
  int*   cursor  = (int*)alloc((size_t)n * 4);
  int*   bsum    = (int*)alloc(256 * 4);
  int*   bpref   = (int*)alloc(256 * 4);
  ull*   ce      = (ull*)alloc((size_t)e * 8);
  if (off > ws_size) return;  // ws too small: bail loudly

  const int nb = (n + 255) / 256;  // 196

  hipMemsetAsync(deg, 0, (size_t)n * 4, stream);
  k_count<<<(e + 255) / 256, 256, 0, stream>>>(dst, deg, e);
  k_bsum<<<nb, 256, 0, stream>>>(deg, bsum, n);
  k_bscan<<<1, 256, 0, stream>>>(bsum, bpref, nb, row_ptr, n);
  k_prefix<<<nb, 256, 0, stream>>>(deg, bpref, row_ptr, cursor, n);
  k_fill<<<(e + 255) / 256, 256, 0, stream>>>(src, dst, cursor, ce, e);

  const int g4  = n / 4;    // 12500 (N%4==0)
  const int g8  = n / 8;    // 6250
  const int g16 = n / 16;   // 3125

  k_enc_ln<<<g4, 256, 0, stream>>>(x, W_enc, b_enc, ln_g, ln_b, hlnA);

  float* hln = hlnA;
  float* hln_next = hlnB;
  for (int l = 0; l < 3; l++) {
    TF2 kin  = tf2x32(0u, 1234u, 0u, (unsigned)(2 * l));      // fold_in(key(1234), 2l)
    TF2 kout = tf2x32(0u, 1234u, 0u, (unsigned)(2 * l + 1));  // fold_in(key(1234), 2l+1)

    // env-conv projections (independent of keep decisions)
    k_projE<<<1250, 256, 0, stream>>>(hln, env_W + (size_t)l * 128 * 64,
                                      env_b + (size_t)l * 64, Htop, Pbot, g4);
    // action path
    k_proj<<<1250, 256, 0, stream>>>(hln, in_W1, out_W1, P1, S1, g4);
    k_gatherA<<<g8, 256, 0, stream>>>(P1, S1, row_ptr, ce, in_b1, out_b1,
                                      in_W2, out_W2, P2S2);
    k_gatherB<<<g16, 256, 0, stream>>>(P2S2, row_ptr, ce, in_b2, out_b2,
                                       keep_i, keep_o, kin.a, kin.b, kout.a, kout.b);
    // env layer
    if (l < 2) {
      k_aggD<true><<<g4, 256, 0, stream>>>(Htop, Pbot, row_ptr, ce, keep_i, keep_o,
                                           out_ew + (size_t)l * e, ln_g, ln_b, hln_next);
    } else {
      k_aggD<false><<<g4, 256, 0, stream>>>(Htop, Pbot, row_ptr, ce, keep_i, keep_o,
                                            out_ew + (size_t)l * e, ln_g, ln_b, hln_next);
    }
    float* tmp = hln; hln = hln_next; hln_next = tmp;
  }

  k_dec<<<g8, 256, 0, stream>>>(hln, W_dec, b_dec, out_h);
}